// Round 1
// baseline (296.781 us; speedup 1.0000x reference)
//
#include <hip/hip_runtime.h>
#include <stdint.h>

#define KTOP 4096
#define H1_SIZE 4096           // histogram over top 12 bits of ordered key
#define H2_SIZE (1u << 20)     // histogram over low 20 bits within boundary bucket
#define CAND_MAX 8192

// ---- workspace layout (bytes) ----
// [0, 4194304)            hist2 (1M x u32)           -- zeroed each call
// [4194304, 4210688)      hist1 (4096 x u32)         -- zeroed each call
// [4210688, 4214784)      chunk sums (1024 x u32)    -- fully overwritten
// [4214784, 4214816)      scalars: 0=b*,1=count_above,2=u*,3=cand_count -- zeroed
// [4214816, 4280352)      candidates (8192 x u64)
// [4280352, +4n)          u array (optional)
#define WS_H2    0
#define WS_H1    4194304
#define WS_CHNK  4210688
#define WS_SCAL  4214784
#define WS_CAND  4214816
#define WS_ZERO  4214816
#define WS_U     4280352

__device__ __forceinline__ uint32_t f2u(float f) {
    uint32_t b = __float_as_uint(f);
    return (b & 0x80000000u) ? ~b : (b | 0x80000000u);
}

__device__ __forceinline__ uint4 group_u(const uint32_t* __restrict__ u_arr,
                                         const float* __restrict__ cls, int g) {
    if (u_arr) return ((const uint4*)u_arr)[g];
    const float4* p = (const float4*)(cls + (size_t)g * 12);
    float4 a = p[0], b = p[1], c = p[2];
    uint4 u;
    u.x = f2u(fmaxf(fmaxf(a.x, a.y), a.z));
    u.y = f2u(fmaxf(fmaxf(a.w, b.x), b.y));
    u.z = f2u(fmaxf(fmaxf(b.z, b.w), c.x));
    u.w = f2u(fmaxf(fmaxf(c.y, c.z), c.w));
    return u;
}

__device__ __forceinline__ uint32_t scalar_u(const float* __restrict__ cls, int i) {
    const float* p = cls + (size_t)i * 3;
    return f2u(fmaxf(fmaxf(p[0], p[1]), p[2]));
}

// K1: compute ordered keys, optional store, 12-bit-prefix histogram (LDS agg).
__global__ void k1_keys_hist(const float* __restrict__ cls,
                             uint32_t* __restrict__ u_arr,
                             uint32_t* __restrict__ hist1, int n) {
    __shared__ uint32_t lh[H1_SIZE];
    for (int i = threadIdx.x; i < H1_SIZE; i += blockDim.x) lh[i] = 0u;
    __syncthreads();
    int nq = n >> 2;
    int stride = gridDim.x * blockDim.x;
    for (int g = blockIdx.x * blockDim.x + threadIdx.x; g < nq; g += stride) {
        const float4* p = (const float4*)(cls + (size_t)g * 12);
        float4 a = p[0], b = p[1], c = p[2];
        uint4 u;
        u.x = f2u(fmaxf(fmaxf(a.x, a.y), a.z));
        u.y = f2u(fmaxf(fmaxf(a.w, b.x), b.y));
        u.z = f2u(fmaxf(fmaxf(b.z, b.w), c.x));
        u.w = f2u(fmaxf(fmaxf(c.y, c.z), c.w));
        if (u_arr) ((uint4*)u_arr)[g] = u;
        atomicAdd(&lh[u.x >> 20], 1u);
        atomicAdd(&lh[u.y >> 20], 1u);
        atomicAdd(&lh[u.z >> 20], 1u);
        atomicAdd(&lh[u.w >> 20], 1u);
    }
    int rem = n & 3;
    if (blockIdx.x == 0 && (int)threadIdx.x < rem) {
        int i = (n & ~3) + threadIdx.x;
        uint32_t uu = scalar_u(cls, i);
        if (u_arr) u_arr[i] = uu;
        atomicAdd(&hist1[uu >> 20], 1u);
    }
    __syncthreads();
    for (int i = threadIdx.x; i < H1_SIZE; i += blockDim.x) {
        uint32_t v = lh[i];
        if (v) atomicAdd(&hist1[i], v);
    }
}

// K2: suffix-scan hist1 from the top; find boundary 12-bit bucket b*.
__global__ void __launch_bounds__(1024) k2_scan1(const uint32_t* __restrict__ hist1,
                                                 uint32_t* __restrict__ scal) {
    __shared__ uint32_t ps[1024];
    int t = threadIdx.x;
    uint32_t h0 = hist1[4 * t], h1 = hist1[4 * t + 1];
    uint32_t h2 = hist1[4 * t + 2], h3 = hist1[4 * t + 3];
    uint32_t sum = h0 + h1 + h2 + h3;
    ps[t] = sum;
    for (int off = 1; off < 1024; off <<= 1) {
        __syncthreads();
        uint32_t v = (t + off < 1024) ? ps[t + off] : 0u;
        __syncthreads();
        ps[t] += v;
    }
    uint32_t incl = ps[t];
    uint32_t excl = incl - sum;           // S(4t+4)
    if (excl < KTOP && incl >= KTOP) {    // unique crossing thread
        uint32_t hh[4] = {h0, h1, h2, h3};
        uint32_t s = excl;
        for (int j = 3; j >= 0; --j) {
            uint32_t ns = s + hh[j];
            if (ns >= KTOP) { scal[0] = (uint32_t)(4 * t + j); scal[1] = s; break; }
            s = ns;
        }
    }
}

// K3: histogram low 20 bits for keys in boundary bucket.
__global__ void k3_hist2(const uint32_t* __restrict__ u_arr,
                         const float* __restrict__ cls,
                         const uint32_t* __restrict__ scal,
                         uint32_t* __restrict__ hist2, int n) {
    uint32_t bstar = scal[0];
    int nq = n >> 2;
    int stride = gridDim.x * blockDim.x;
    for (int g = blockIdx.x * blockDim.x + threadIdx.x; g < nq; g += stride) {
        uint4 u = group_u(u_arr, cls, g);
        if ((u.x >> 20) == bstar) atomicAdd(&hist2[u.x & 0xFFFFFu], 1u);
        if ((u.y >> 20) == bstar) atomicAdd(&hist2[u.y & 0xFFFFFu], 1u);
        if ((u.z >> 20) == bstar) atomicAdd(&hist2[u.z & 0xFFFFFu], 1u);
        if ((u.w >> 20) == bstar) atomicAdd(&hist2[u.w & 0xFFFFFu], 1u);
    }
    int rem = n & 3;
    if (blockIdx.x == 0 && (int)threadIdx.x < rem) {
        int i = (n & ~3) + threadIdx.x;
        uint32_t uu = u_arr ? u_arr[i] : scalar_u(cls, i);
        if ((uu >> 20) == bstar) atomicAdd(&hist2[uu & 0xFFFFFu], 1u);
    }
}

// K4a: per-chunk (1024 bins) sums of hist2.
__global__ void k4a_chunks(const uint32_t* __restrict__ hist2,
                           uint32_t* __restrict__ chunks) {
    __shared__ uint32_t red[256];
    int c = blockIdx.x;
    uint32_t s = 0;
    for (int i = threadIdx.x; i < 1024; i += 256) s += hist2[c * 1024 + i];
    red[threadIdx.x] = s;
    __syncthreads();
    for (int off = 128; off > 0; off >>= 1) {
        if ((int)threadIdx.x < off) red[threadIdx.x] += red[threadIdx.x + off];
        __syncthreads();
    }
    if (threadIdx.x == 0) chunks[c] = red[0];
}

// K4b: resolve exact 32-bit threshold u*.
__global__ void __launch_bounds__(1024) k4b_scan2(const uint32_t* __restrict__ hist2,
                                                  const uint32_t* __restrict__ chunks,
                                                  uint32_t* __restrict__ scal) {
    __shared__ uint32_t ps[1024];
    __shared__ uint32_t sh_c, sh_base;
    int t = threadIdx.x;
    uint32_t krem = (uint32_t)KTOP - scal[1];   // >= 1
    uint32_t cs = chunks[t];
    ps[t] = cs;
    for (int off = 1; off < 1024; off <<= 1) {
        __syncthreads();
        uint32_t v = (t + off < 1024) ? ps[t + off] : 0u;
        __syncthreads();
        ps[t] += v;
    }
    uint32_t incl = ps[t];
    uint32_t excl = incl - cs;
    if (excl < krem && incl >= krem) { sh_c = (uint32_t)t; sh_base = excl; }
    __syncthreads();
    uint32_t c = sh_c, base = sh_base;
    uint32_t h = hist2[c * 1024 + t];
    ps[t] = h;
    for (int off = 1; off < 1024; off <<= 1) {
        __syncthreads();
        uint32_t v = (t + off < 1024) ? ps[t + off] : 0u;
        __syncthreads();
        ps[t] += v;
    }
    uint32_t incl2 = ps[t] + base;
    uint32_t excl2 = incl2 - h;
    if (excl2 < krem && incl2 >= krem) {
        uint32_t L = c * 1024 + (uint32_t)t;
        scal[2] = (scal[0] << 20) | L;
    }
}

// K5: compact all keys >= u* as 64-bit sortable (u<<32)|~idx.
__global__ void k5_compact(const uint32_t* __restrict__ u_arr,
                           const float* __restrict__ cls,
                           const uint32_t* __restrict__ scal,
                           uint64_t* __restrict__ cand,
                           uint32_t* __restrict__ cnt, int n) {
    uint32_t ustar = scal[2];
    int nq = n >> 2;
    int stride = gridDim.x * blockDim.x;
    for (int g = blockIdx.x * blockDim.x + threadIdx.x; g < nq; g += stride) {
        uint4 u = group_u(u_arr, cls, g);
        uint32_t b = (uint32_t)g * 4u;
        if (u.x >= ustar) { uint32_t p = atomicAdd(cnt, 1u); if (p < CAND_MAX) cand[p] = ((uint64_t)u.x << 32) | (uint32_t)~(b + 0u); }
        if (u.y >= ustar) { uint32_t p = atomicAdd(cnt, 1u); if (p < CAND_MAX) cand[p] = ((uint64_t)u.y << 32) | (uint32_t)~(b + 1u); }
        if (u.z >= ustar) { uint32_t p = atomicAdd(cnt, 1u); if (p < CAND_MAX) cand[p] = ((uint64_t)u.z << 32) | (uint32_t)~(b + 2u); }
        if (u.w >= ustar) { uint32_t p = atomicAdd(cnt, 1u); if (p < CAND_MAX) cand[p] = ((uint64_t)u.w << 32) | (uint32_t)~(b + 3u); }
    }
    int rem = n & 3;
    if (blockIdx.x == 0 && (int)threadIdx.x < rem) {
        int i = (n & ~3) + threadIdx.x;
        uint32_t uu = u_arr ? u_arr[i] : scalar_u(cls, i);
        if (uu >= ustar) { uint32_t p = atomicAdd(cnt, 1u); if (p < CAND_MAX) cand[p] = ((uint64_t)uu << 32) | (uint32_t)~((uint32_t)i); }
    }
}

// K6: one block — bitonic sort candidates descending, emit outputs.
__global__ void __launch_bounds__(1024) k6_sort_out(const uint64_t* __restrict__ cand,
                                                    const uint32_t* __restrict__ cnt,
                                                    const float* __restrict__ cls,
                                                    const float* __restrict__ box,
                                                    float* __restrict__ out) {
    __shared__ uint64_t s[CAND_MAX];
    uint32_t m = *cnt;
    if (m > CAND_MAX) m = CAND_MAX;
    for (int i = threadIdx.x; i < CAND_MAX; i += 1024)
        s[i] = (i < (int)m) ? cand[i] : 0ull;
    __syncthreads();
    for (int k = 2; k <= CAND_MAX; k <<= 1) {
        for (int j = k >> 1; j > 0; j >>= 1) {
            for (int i = threadIdx.x; i < CAND_MAX; i += 1024) {
                int ixj = i ^ j;
                if (ixj > i) {
                    uint64_t a = s[i], b = s[ixj];
                    bool desc = ((i & k) == 0);
                    bool sw = desc ? (a < b) : (a > b);
                    if (sw) { s[i] = b; s[ixj] = a; }
                }
            }
            __syncthreads();
        }
    }
    for (int i = threadIdx.x; i < KTOP; i += 1024) {
        uint64_t key = s[i];
        uint32_t idx = ~(uint32_t)key;
        const float* cp = cls + (size_t)idx * 3;
        float c0 = cp[0], c1 = cp[1], c2 = cp[2];
        float mx = c0; int lab = 1;
        if (c1 > mx) { mx = c1; lab = 2; }
        if (c2 > mx) { mx = c2; lab = 3; }
        out[i] = mx;                                  // top_scores
        const float* bp = box + (size_t)idx * 7;
        float* op = out + KTOP + (size_t)i * 7;       // top_boxes
        #pragma unroll
        for (int j = 0; j < 7; ++j) op[j] = bp[j];
        out[KTOP * 8 + i] = (float)lab;               // top_labels
    }
}

extern "C" void kernel_launch(void* const* d_in, const int* in_sizes, int n_in,
                              void* d_out, int out_size, void* d_ws, size_t ws_size,
                              hipStream_t stream) {
    const float* cls = (const float*)d_in[0];
    const float* box = (const float*)d_in[1];
    float* out = (float*)d_out;
    int n = in_sizes[0] / 3;

    char* ws = (char*)d_ws;
    uint32_t* hist2  = (uint32_t*)(ws + WS_H2);
    uint32_t* hist1  = (uint32_t*)(ws + WS_H1);
    uint32_t* chunks = (uint32_t*)(ws + WS_CHNK);
    uint32_t* scal   = (uint32_t*)(ws + WS_SCAL);
    uint64_t* cand   = (uint64_t*)(ws + WS_CAND);
    uint32_t* u_arr  = nullptr;
    if (ws_size >= (size_t)WS_U + (size_t)n * 4u)
        u_arr = (uint32_t*)(ws + WS_U);

    hipMemsetAsync(d_ws, 0, WS_ZERO + 32, stream);

    const int blocks = 2048, threads = 256;
    k1_keys_hist<<<blocks, threads, 0, stream>>>(cls, u_arr, hist1, n);
    k2_scan1<<<1, 1024, 0, stream>>>(hist1, scal);
    k3_hist2<<<blocks, threads, 0, stream>>>(u_arr, cls, scal, hist2, n);
    k4a_chunks<<<1024, 256, 0, stream>>>(hist2, chunks);
    k4b_scan2<<<1, 1024, 0, stream>>>(hist2, chunks, scal);
    k5_compact<<<blocks, threads, 0, stream>>>(u_arr, cls, scal, cand, &scal[3], n);
    k6_sort_out<<<1, 1024, 0, stream>>>(cand, &scal[3], cls, box, out);
}

// Round 2
// 247.097 us; speedup vs baseline: 1.2011x; 1.2011x over previous
//
#include <hip/hip_runtime.h>
#include <stdint.h>

#define KTOP 4096
#define H1_SIZE 4096           // histogram over top 12 bits of ordered key
#define H2_SIZE (1u << 20)     // histogram over low 20 bits within boundary bucket
#define CAND_MAX 8192

// ---- workspace layout (bytes) ----
// [0, 4194304)            hist2 (1M x u32)           -- zeroed each call
// [4194304, 4210688)      hist1 (4096 x u32)         -- zeroed each call
// [4210688, 4214784)      chunk sums (1024 x u32)    -- fully overwritten
// [4214784, 4214816)      scalars: 0=b*,1=count_above,2=u*,3=cand_count -- zeroed
// [4214816, 4280352)      candidates (8192 x u64)
// [4280352, +4n)          u array (optional)
#define WS_H2    0
#define WS_H1    4194304
#define WS_CHNK  4210688
#define WS_SCAL  4214784
#define WS_CAND  4214816
#define WS_ZERO  4214816
#define WS_U     4280352

__device__ __forceinline__ uint32_t f2u(float f) {
    uint32_t b = __float_as_uint(f);
    return (b & 0x80000000u) ? ~b : (b | 0x80000000u);
}

__device__ __forceinline__ float u2f(uint32_t u) {
    uint32_t b = (u & 0x80000000u) ? (u ^ 0x80000000u) : ~u;
    return __uint_as_float(b);
}

__device__ __forceinline__ uint4 group_u(const uint32_t* __restrict__ u_arr,
                                         const float* __restrict__ cls, int g) {
    if (u_arr) return ((const uint4*)u_arr)[g];
    const float4* p = (const float4*)(cls + (size_t)g * 12);
    float4 a = p[0], b = p[1], c = p[2];
    uint4 u;
    u.x = f2u(fmaxf(fmaxf(a.x, a.y), a.z));
    u.y = f2u(fmaxf(fmaxf(a.w, b.x), b.y));
    u.z = f2u(fmaxf(fmaxf(b.z, b.w), c.x));
    u.w = f2u(fmaxf(fmaxf(c.y, c.z), c.w));
    return u;
}

__device__ __forceinline__ uint32_t scalar_u(const float* __restrict__ cls, int i) {
    const float* p = cls + (size_t)i * 3;
    return f2u(fmaxf(fmaxf(p[0], p[1]), p[2]));
}

// K1: compute ordered keys, optional store, 12-bit-prefix histogram (LDS agg).
__global__ void k1_keys_hist(const float* __restrict__ cls,
                             uint32_t* __restrict__ u_arr,
                             uint32_t* __restrict__ hist1, int n) {
    __shared__ uint32_t lh[H1_SIZE];
    for (int i = threadIdx.x; i < H1_SIZE; i += blockDim.x) lh[i] = 0u;
    __syncthreads();
    int nq = n >> 2;
    int stride = gridDim.x * blockDim.x;
    for (int g = blockIdx.x * blockDim.x + threadIdx.x; g < nq; g += stride) {
        const float4* p = (const float4*)(cls + (size_t)g * 12);
        float4 a = p[0], b = p[1], c = p[2];
        uint4 u;
        u.x = f2u(fmaxf(fmaxf(a.x, a.y), a.z));
        u.y = f2u(fmaxf(fmaxf(a.w, b.x), b.y));
        u.z = f2u(fmaxf(fmaxf(b.z, b.w), c.x));
        u.w = f2u(fmaxf(fmaxf(c.y, c.z), c.w));
        if (u_arr) ((uint4*)u_arr)[g] = u;
        atomicAdd(&lh[u.x >> 20], 1u);
        atomicAdd(&lh[u.y >> 20], 1u);
        atomicAdd(&lh[u.z >> 20], 1u);
        atomicAdd(&lh[u.w >> 20], 1u);
    }
    int rem = n & 3;
    if (blockIdx.x == 0 && (int)threadIdx.x < rem) {
        int i = (n & ~3) + threadIdx.x;
        uint32_t uu = scalar_u(cls, i);
        if (u_arr) u_arr[i] = uu;
        atomicAdd(&hist1[uu >> 20], 1u);
    }
    __syncthreads();
    for (int i = threadIdx.x; i < H1_SIZE; i += blockDim.x) {
        uint32_t v = lh[i];
        if (v) atomicAdd(&hist1[i], v);
    }
}

// K2: suffix-scan hist1 from the top; find boundary 12-bit bucket b*.
__global__ void __launch_bounds__(1024) k2_scan1(const uint32_t* __restrict__ hist1,
                                                 uint32_t* __restrict__ scal) {
    __shared__ uint32_t ps[1024];
    int t = threadIdx.x;
    uint32_t h0 = hist1[4 * t], h1 = hist1[4 * t + 1];
    uint32_t h2 = hist1[4 * t + 2], h3 = hist1[4 * t + 3];
    uint32_t sum = h0 + h1 + h2 + h3;
    ps[t] = sum;
    for (int off = 1; off < 1024; off <<= 1) {
        __syncthreads();
        uint32_t v = (t + off < 1024) ? ps[t + off] : 0u;
        __syncthreads();
        ps[t] += v;
    }
    uint32_t incl = ps[t];
    uint32_t excl = incl - sum;           // S(4t+4)
    if (excl < KTOP && incl >= KTOP) {    // unique crossing thread
        uint32_t hh[4] = {h0, h1, h2, h3};
        uint32_t s = excl;
        for (int j = 3; j >= 0; --j) {
            uint32_t ns = s + hh[j];
            if (ns >= KTOP) { scal[0] = (uint32_t)(4 * t + j); scal[1] = s; break; }
            s = ns;
        }
    }
}

// K3: histogram low 20 bits for keys in boundary bucket.
__global__ void k3_hist2(const uint32_t* __restrict__ u_arr,
                         const float* __restrict__ cls,
                         const uint32_t* __restrict__ scal,
                         uint32_t* __restrict__ hist2, int n) {
    uint32_t bstar = scal[0];
    int nq = n >> 2;
    int stride = gridDim.x * blockDim.x;
    for (int g = blockIdx.x * blockDim.x + threadIdx.x; g < nq; g += stride) {
        uint4 u = group_u(u_arr, cls, g);
        if ((u.x >> 20) == bstar) atomicAdd(&hist2[u.x & 0xFFFFFu], 1u);
        if ((u.y >> 20) == bstar) atomicAdd(&hist2[u.y & 0xFFFFFu], 1u);
        if ((u.z >> 20) == bstar) atomicAdd(&hist2[u.z & 0xFFFFFu], 1u);
        if ((u.w >> 20) == bstar) atomicAdd(&hist2[u.w & 0xFFFFFu], 1u);
    }
    int rem = n & 3;
    if (blockIdx.x == 0 && (int)threadIdx.x < rem) {
        int i = (n & ~3) + threadIdx.x;
        uint32_t uu = u_arr ? u_arr[i] : scalar_u(cls, i);
        if ((uu >> 20) == bstar) atomicAdd(&hist2[uu & 0xFFFFFu], 1u);
    }
}

// K4a: per-chunk (1024 bins) sums of hist2.
__global__ void k4a_chunks(const uint32_t* __restrict__ hist2,
                           uint32_t* __restrict__ chunks) {
    __shared__ uint32_t red[256];
    int c = blockIdx.x;
    uint32_t s = 0;
    for (int i = threadIdx.x; i < 1024; i += 256) s += hist2[c * 1024 + i];
    red[threadIdx.x] = s;
    __syncthreads();
    for (int off = 128; off > 0; off >>= 1) {
        if ((int)threadIdx.x < off) red[threadIdx.x] += red[threadIdx.x + off];
        __syncthreads();
    }
    if (threadIdx.x == 0) chunks[c] = red[0];
}

// K4b: resolve exact 32-bit threshold u*.
__global__ void __launch_bounds__(1024) k4b_scan2(const uint32_t* __restrict__ hist2,
                                                  const uint32_t* __restrict__ chunks,
                                                  uint32_t* __restrict__ scal) {
    __shared__ uint32_t ps[1024];
    __shared__ uint32_t sh_c, sh_base;
    int t = threadIdx.x;
    uint32_t krem = (uint32_t)KTOP - scal[1];   // >= 1
    uint32_t cs = chunks[t];
    ps[t] = cs;
    for (int off = 1; off < 1024; off <<= 1) {
        __syncthreads();
        uint32_t v = (t + off < 1024) ? ps[t + off] : 0u;
        __syncthreads();
        ps[t] += v;
    }
    uint32_t incl = ps[t];
    uint32_t excl = incl - cs;
    if (excl < krem && incl >= krem) { sh_c = (uint32_t)t; sh_base = excl; }
    __syncthreads();
    uint32_t c = sh_c, base = sh_base;
    uint32_t h = hist2[c * 1024 + t];
    ps[t] = h;
    for (int off = 1; off < 1024; off <<= 1) {
        __syncthreads();
        uint32_t v = (t + off < 1024) ? ps[t + off] : 0u;
        __syncthreads();
        ps[t] += v;
    }
    uint32_t incl2 = ps[t] + base;
    uint32_t excl2 = incl2 - h;
    if (excl2 < krem && incl2 >= krem) {
        uint32_t L = c * 1024 + (uint32_t)t;
        scal[2] = (scal[0] << 20) | L;
    }
}

// K5: compact all keys >= u* as 64-bit sortable (u<<32)|~idx.
__global__ void k5_compact(const uint32_t* __restrict__ u_arr,
                           const float* __restrict__ cls,
                           const uint32_t* __restrict__ scal,
                           uint64_t* __restrict__ cand,
                           uint32_t* __restrict__ cnt, int n) {
    uint32_t ustar = scal[2];
    int nq = n >> 2;
    int stride = gridDim.x * blockDim.x;
    for (int g = blockIdx.x * blockDim.x + threadIdx.x; g < nq; g += stride) {
        uint4 u = group_u(u_arr, cls, g);
        uint32_t b = (uint32_t)g * 4u;
        if (u.x >= ustar) { uint32_t p = atomicAdd(cnt, 1u); if (p < CAND_MAX) cand[p] = ((uint64_t)u.x << 32) | (uint32_t)~(b + 0u); }
        if (u.y >= ustar) { uint32_t p = atomicAdd(cnt, 1u); if (p < CAND_MAX) cand[p] = ((uint64_t)u.y << 32) | (uint32_t)~(b + 1u); }
        if (u.z >= ustar) { uint32_t p = atomicAdd(cnt, 1u); if (p < CAND_MAX) cand[p] = ((uint64_t)u.z << 32) | (uint32_t)~(b + 2u); }
        if (u.w >= ustar) { uint32_t p = atomicAdd(cnt, 1u); if (p < CAND_MAX) cand[p] = ((uint64_t)u.w << 32) | (uint32_t)~(b + 3u); }
    }
    int rem = n & 3;
    if (blockIdx.x == 0 && (int)threadIdx.x < rem) {
        int i = (n & ~3) + threadIdx.x;
        uint32_t uu = u_arr ? u_arr[i] : scalar_u(cls, i);
        if (uu >= ustar) { uint32_t p = atomicAdd(cnt, 1u); if (p < CAND_MAX) cand[p] = ((uint64_t)uu << 32) | (uint32_t)~((uint32_t)i); }
    }
}

// K6: counting-rank over unique 64-bit keys — no sort needed.
// Each block stages all m candidates in LDS (broadcast-read, conflict-free);
// thread handles one candidate: rank = #{j : key_j > key_i}; rank < KTOP
// is exactly the (value desc, index asc) top-k position. Writes outputs
// directly (scores reconstructed bit-exact from key; labels recomputed
// with first-max semantics; boxes gathered).
__global__ void __launch_bounds__(1024) k6_rank_out(const uint64_t* __restrict__ cand,
                                                    const uint32_t* __restrict__ cnt,
                                                    const float* __restrict__ cls,
                                                    const float* __restrict__ box,
                                                    float* __restrict__ out) {
    __shared__ uint64_t s[CAND_MAX];
    uint32_t m = *cnt;
    if (m > CAND_MAX) m = CAND_MAX;
    for (int i = threadIdx.x; i < CAND_MAX; i += 1024)
        s[i] = (i < (int)m) ? cand[i] : 0ull;   // pad 0: real keys have bit63 set
    __syncthreads();
    int i = blockIdx.x * 1024 + threadIdx.x;
    if (i >= (int)m) return;
    uint64_t key = s[i];
    uint32_t rank = 0;
    int mm = (int)m;
    int mm8 = mm & ~7;
    int j = 0;
    for (; j < mm8; j += 8) {
        rank += (uint32_t)(s[j + 0] > key);
        rank += (uint32_t)(s[j + 1] > key);
        rank += (uint32_t)(s[j + 2] > key);
        rank += (uint32_t)(s[j + 3] > key);
        rank += (uint32_t)(s[j + 4] > key);
        rank += (uint32_t)(s[j + 5] > key);
        rank += (uint32_t)(s[j + 6] > key);
        rank += (uint32_t)(s[j + 7] > key);
    }
    for (; j < mm; ++j) rank += (uint32_t)(s[j] > key);
    if (rank < KTOP) {
        uint32_t idx = ~(uint32_t)key;
        uint32_t u = (uint32_t)(key >> 32);
        out[rank] = u2f(u);                               // top_scores (bit-exact)
        const float* cp = cls + (size_t)idx * 3;
        float c0 = cp[0], c1 = cp[1], c2 = cp[2];
        float mx = c0; int lab = 1;
        if (c1 > mx) { mx = c1; lab = 2; }
        if (c2 > mx) { mx = c2; lab = 3; }
        const float* bp = box + (size_t)idx * 7;
        float* op = out + KTOP + (size_t)rank * 7;        // top_boxes
        #pragma unroll
        for (int q = 0; q < 7; ++q) op[q] = bp[q];
        out[KTOP * 8 + rank] = (float)lab;                // top_labels
    }
}

extern "C" void kernel_launch(void* const* d_in, const int* in_sizes, int n_in,
                              void* d_out, int out_size, void* d_ws, size_t ws_size,
                              hipStream_t stream) {
    const float* cls = (const float*)d_in[0];
    const float* box = (const float*)d_in[1];
    float* out = (float*)d_out;
    int n = in_sizes[0] / 3;

    char* ws = (char*)d_ws;
    uint32_t* hist2  = (uint32_t*)(ws + WS_H2);
    uint32_t* hist1  = (uint32_t*)(ws + WS_H1);
    uint32_t* chunks = (uint32_t*)(ws + WS_CHNK);
    uint32_t* scal   = (uint32_t*)(ws + WS_SCAL);
    uint64_t* cand   = (uint64_t*)(ws + WS_CAND);
    uint32_t* u_arr  = nullptr;
    if (ws_size >= (size_t)WS_U + (size_t)n * 4u)
        u_arr = (uint32_t*)(ws + WS_U);

    hipMemsetAsync(d_ws, 0, WS_ZERO + 32, stream);

    const int blocks = 2048, threads = 256;
    k1_keys_hist<<<blocks, threads, 0, stream>>>(cls, u_arr, hist1, n);
    k2_scan1<<<1, 1024, 0, stream>>>(hist1, scal);
    k3_hist2<<<blocks, threads, 0, stream>>>(u_arr, cls, scal, hist2, n);
    k4a_chunks<<<1024, 256, 0, stream>>>(hist2, chunks);
    k4b_scan2<<<1, 1024, 0, stream>>>(hist2, chunks, scal);
    k5_compact<<<blocks, threads, 0, stream>>>(u_arr, cls, scal, cand, &scal[3], n);
    k6_rank_out<<<(CAND_MAX + 1023) / 1024, 1024, 0, stream>>>(cand, &scal[3], cls, box, out);
}

// Round 3
// 246.694 us; speedup vs baseline: 1.2030x; 1.0016x over previous
//
#include <hip/hip_runtime.h>
#include <stdint.h>

#define KTOP 4096
#define H1_SIZE 4096           // histogram over top 12 bits of ordered key
#define H2_SIZE (1u << 20)     // histogram over low 20 bits within boundary bucket
#define CAND_MAX 8192

// ---- workspace layout (bytes) ----
// [0, 4194304)            hist2 (1M x u32)           -- zeroed inside k1
// [4194304, 4210688)      hist1 (4096 x u32)         -- zeroed by z0
// [4210688, 4214784)      chunk sums (1024 x u32)    -- fully overwritten
// [4214784, 4214816)      scalars: 0=b*,1=count_above,2=u*,3=cand_count -- zeroed by z0
// [4214816, 4280352)      candidates (8192 x u64)    -- no zeroing needed
// [4280352, +4n)          u array (optional)
#define WS_H2    0
#define WS_H1    4194304
#define WS_CHNK  4210688
#define WS_SCAL  4214784
#define WS_CAND  4214816
#define WS_U     4280352

__device__ __forceinline__ uint32_t f2u(float f) {
    uint32_t b = __float_as_uint(f);
    return (b & 0x80000000u) ? ~b : (b | 0x80000000u);
}

__device__ __forceinline__ float u2f(uint32_t u) {
    uint32_t b = (u & 0x80000000u) ? (u ^ 0x80000000u) : ~u;
    return __uint_as_float(b);
}

__device__ __forceinline__ uint4 group_u(const uint32_t* __restrict__ u_arr,
                                         const float* __restrict__ cls, int g) {
    if (u_arr) return ((const uint4*)u_arr)[g];
    const float4* p = (const float4*)(cls + (size_t)g * 12);
    float4 a = p[0], b = p[1], c = p[2];
    uint4 u;
    u.x = f2u(fmaxf(fmaxf(a.x, a.y), a.z));
    u.y = f2u(fmaxf(fmaxf(a.w, b.x), b.y));
    u.z = f2u(fmaxf(fmaxf(b.z, b.w), c.x));
    u.w = f2u(fmaxf(fmaxf(c.y, c.z), c.w));
    return u;
}

__device__ __forceinline__ uint32_t scalar_u(const float* __restrict__ cls, int i) {
    const float* p = cls + (size_t)i * 3;
    return f2u(fmaxf(fmaxf(p[0], p[1]), p[2]));
}

// z0: zero hist1 + scalars (16.4 KB). Must finish before k1 (separate launch).
__global__ void z0_zero_small(uint32_t* __restrict__ hist1,
                              uint32_t* __restrict__ scal) {
    int t = blockIdx.x * blockDim.x + threadIdx.x;
    if (t < H1_SIZE) hist1[t] = 0u;
    if (t < 8) scal[t] = 0u;
}

// K1: zero hist2 (grid-strided; consumer k3 runs after kernel boundary),
// compute ordered keys, store u_arr, 12-bit-prefix histogram (LDS agg).
__global__ void k1_keys_hist(const float* __restrict__ cls,
                             uint32_t* __restrict__ u_arr,
                             uint32_t* __restrict__ hist1,
                             uint32_t* __restrict__ hist2, int n) {
    __shared__ uint32_t lh[H1_SIZE];
    int stride = gridDim.x * blockDim.x;
    // zero hist2 cooperatively (1M u32 = 256K uint4)
    {
        uint4 z = make_uint4(0u, 0u, 0u, 0u);
        uint4* h2v = (uint4*)hist2;
        for (int i = blockIdx.x * blockDim.x + threadIdx.x; i < (int)(H2_SIZE / 4); i += stride)
            h2v[i] = z;
    }
    for (int i = threadIdx.x; i < H1_SIZE; i += blockDim.x) lh[i] = 0u;
    __syncthreads();
    int nq = n >> 2;
    for (int g = blockIdx.x * blockDim.x + threadIdx.x; g < nq; g += stride) {
        const float4* p = (const float4*)(cls + (size_t)g * 12);
        float4 a = p[0], b = p[1], c = p[2];
        uint4 u;
        u.x = f2u(fmaxf(fmaxf(a.x, a.y), a.z));
        u.y = f2u(fmaxf(fmaxf(a.w, b.x), b.y));
        u.z = f2u(fmaxf(fmaxf(b.z, b.w), c.x));
        u.w = f2u(fmaxf(fmaxf(c.y, c.z), c.w));
        if (u_arr) ((uint4*)u_arr)[g] = u;
        atomicAdd(&lh[u.x >> 20], 1u);
        atomicAdd(&lh[u.y >> 20], 1u);
        atomicAdd(&lh[u.z >> 20], 1u);
        atomicAdd(&lh[u.w >> 20], 1u);
    }
    int rem = n & 3;
    if (blockIdx.x == 0 && (int)threadIdx.x < rem) {
        int i = (n & ~3) + threadIdx.x;
        uint32_t uu = scalar_u(cls, i);
        if (u_arr) u_arr[i] = uu;
        atomicAdd(&hist1[uu >> 20], 1u);
    }
    __syncthreads();
    for (int i = threadIdx.x; i < H1_SIZE; i += blockDim.x) {
        uint32_t v = lh[i];
        if (v) atomicAdd(&hist1[i], v);
    }
}

// K2: suffix-scan hist1 from the top; find boundary 12-bit bucket b*.
__global__ void __launch_bounds__(1024) k2_scan1(const uint32_t* __restrict__ hist1,
                                                 uint32_t* __restrict__ scal) {
    __shared__ uint32_t ps[1024];
    int t = threadIdx.x;
    uint32_t h0 = hist1[4 * t], h1 = hist1[4 * t + 1];
    uint32_t h2 = hist1[4 * t + 2], h3 = hist1[4 * t + 3];
    uint32_t sum = h0 + h1 + h2 + h3;
    ps[t] = sum;
    for (int off = 1; off < 1024; off <<= 1) {
        __syncthreads();
        uint32_t v = (t + off < 1024) ? ps[t + off] : 0u;
        __syncthreads();
        ps[t] += v;
    }
    uint32_t incl = ps[t];
    uint32_t excl = incl - sum;           // S(4t+4)
    if (excl < KTOP && incl >= KTOP) {    // unique crossing thread
        uint32_t hh[4] = {h0, h1, h2, h3};
        uint32_t s = excl;
        for (int j = 3; j >= 0; --j) {
            uint32_t ns = s + hh[j];
            if (ns >= KTOP) { scal[0] = (uint32_t)(4 * t + j); scal[1] = s; break; }
            s = ns;
        }
    }
}

// K3: histogram low 20 bits for keys in boundary bucket.
__global__ void k3_hist2(const uint32_t* __restrict__ u_arr,
                         const float* __restrict__ cls,
                         const uint32_t* __restrict__ scal,
                         uint32_t* __restrict__ hist2, int n) {
    uint32_t bstar = scal[0];
    int nq = n >> 2;
    int stride = gridDim.x * blockDim.x;
    for (int g = blockIdx.x * blockDim.x + threadIdx.x; g < nq; g += stride) {
        uint4 u = group_u(u_arr, cls, g);
        if ((u.x >> 20) == bstar) atomicAdd(&hist2[u.x & 0xFFFFFu], 1u);
        if ((u.y >> 20) == bstar) atomicAdd(&hist2[u.y & 0xFFFFFu], 1u);
        if ((u.z >> 20) == bstar) atomicAdd(&hist2[u.z & 0xFFFFFu], 1u);
        if ((u.w >> 20) == bstar) atomicAdd(&hist2[u.w & 0xFFFFFu], 1u);
    }
    int rem = n & 3;
    if (blockIdx.x == 0 && (int)threadIdx.x < rem) {
        int i = (n & ~3) + threadIdx.x;
        uint32_t uu = u_arr ? u_arr[i] : scalar_u(cls, i);
        if ((uu >> 20) == bstar) atomicAdd(&hist2[uu & 0xFFFFFu], 1u);
    }
}

// K4a: per-chunk (1024 bins) sums of hist2.
__global__ void k4a_chunks(const uint32_t* __restrict__ hist2,
                           uint32_t* __restrict__ chunks) {
    __shared__ uint32_t red[256];
    int c = blockIdx.x;
    uint32_t s = 0;
    for (int i = threadIdx.x; i < 1024; i += 256) s += hist2[c * 1024 + i];
    red[threadIdx.x] = s;
    __syncthreads();
    for (int off = 128; off > 0; off >>= 1) {
        if ((int)threadIdx.x < off) red[threadIdx.x] += red[threadIdx.x + off];
        __syncthreads();
    }
    if (threadIdx.x == 0) chunks[c] = red[0];
}

// K4b: resolve exact 32-bit threshold u*.
__global__ void __launch_bounds__(1024) k4b_scan2(const uint32_t* __restrict__ hist2,
                                                  const uint32_t* __restrict__ chunks,
                                                  uint32_t* __restrict__ scal) {
    __shared__ uint32_t ps[1024];
    __shared__ uint32_t sh_c, sh_base;
    int t = threadIdx.x;
    uint32_t krem = (uint32_t)KTOP - scal[1];   // >= 1
    uint32_t cs = chunks[t];
    ps[t] = cs;
    for (int off = 1; off < 1024; off <<= 1) {
        __syncthreads();
        uint32_t v = (t + off < 1024) ? ps[t + off] : 0u;
        __syncthreads();
        ps[t] += v;
    }
    uint32_t incl = ps[t];
    uint32_t excl = incl - cs;
    if (excl < krem && incl >= krem) { sh_c = (uint32_t)t; sh_base = excl; }
    __syncthreads();
    uint32_t c = sh_c, base = sh_base;
    uint32_t h = hist2[c * 1024 + t];
    ps[t] = h;
    for (int off = 1; off < 1024; off <<= 1) {
        __syncthreads();
        uint32_t v = (t + off < 1024) ? ps[t + off] : 0u;
        __syncthreads();
        ps[t] += v;
    }
    uint32_t incl2 = ps[t] + base;
    uint32_t excl2 = incl2 - h;
    if (excl2 < krem && incl2 >= krem) {
        uint32_t L = c * 1024 + (uint32_t)t;
        scal[2] = (scal[0] << 20) | L;
    }
}

// K5: compact all keys >= u* as 64-bit sortable (u<<32)|~idx.
__global__ void k5_compact(const uint32_t* __restrict__ u_arr,
                           const float* __restrict__ cls,
                           const uint32_t* __restrict__ scal,
                           uint64_t* __restrict__ cand,
                           uint32_t* __restrict__ cnt, int n) {
    uint32_t ustar = scal[2];
    int nq = n >> 2;
    int stride = gridDim.x * blockDim.x;
    for (int g = blockIdx.x * blockDim.x + threadIdx.x; g < nq; g += stride) {
        uint4 u = group_u(u_arr, cls, g);
        uint32_t b = (uint32_t)g * 4u;
        if (u.x >= ustar) { uint32_t p = atomicAdd(cnt, 1u); if (p < CAND_MAX) cand[p] = ((uint64_t)u.x << 32) | (uint32_t)~(b + 0u); }
        if (u.y >= ustar) { uint32_t p = atomicAdd(cnt, 1u); if (p < CAND_MAX) cand[p] = ((uint64_t)u.y << 32) | (uint32_t)~(b + 1u); }
        if (u.z >= ustar) { uint32_t p = atomicAdd(cnt, 1u); if (p < CAND_MAX) cand[p] = ((uint64_t)u.z << 32) | (uint32_t)~(b + 2u); }
        if (u.w >= ustar) { uint32_t p = atomicAdd(cnt, 1u); if (p < CAND_MAX) cand[p] = ((uint64_t)u.w << 32) | (uint32_t)~(b + 3u); }
    }
    int rem = n & 3;
    if (blockIdx.x == 0 && (int)threadIdx.x < rem) {
        int i = (n & ~3) + threadIdx.x;
        uint32_t uu = u_arr ? u_arr[i] : scalar_u(cls, i);
        if (uu >= ustar) { uint32_t p = atomicAdd(cnt, 1u); if (p < CAND_MAX) cand[p] = ((uint64_t)uu << 32) | (uint32_t)~((uint32_t)i); }
    }
}

// K6: counting-rank over unique 64-bit keys — no sort needed.
__global__ void __launch_bounds__(1024) k6_rank_out(const uint64_t* __restrict__ cand,
                                                    const uint32_t* __restrict__ cnt,
                                                    const float* __restrict__ cls,
                                                    const float* __restrict__ box,
                                                    float* __restrict__ out) {
    __shared__ uint64_t s[CAND_MAX];
    uint32_t m = *cnt;
    if (m > CAND_MAX) m = CAND_MAX;
    for (int i = threadIdx.x; i < CAND_MAX; i += 1024)
        s[i] = (i < (int)m) ? cand[i] : 0ull;   // pad 0: real keys have bit63 set
    __syncthreads();
    int i = blockIdx.x * 1024 + threadIdx.x;
    if (i >= (int)m) return;
    uint64_t key = s[i];
    uint32_t rank = 0;
    int mm = (int)m;
    int mm8 = mm & ~7;
    int j = 0;
    for (; j < mm8; j += 8) {
        rank += (uint32_t)(s[j + 0] > key);
        rank += (uint32_t)(s[j + 1] > key);
        rank += (uint32_t)(s[j + 2] > key);
        rank += (uint32_t)(s[j + 3] > key);
        rank += (uint32_t)(s[j + 4] > key);
        rank += (uint32_t)(s[j + 5] > key);
        rank += (uint32_t)(s[j + 6] > key);
        rank += (uint32_t)(s[j + 7] > key);
    }
    for (; j < mm; ++j) rank += (uint32_t)(s[j] > key);
    if (rank < KTOP) {
        uint32_t idx = ~(uint32_t)key;
        uint32_t u = (uint32_t)(key >> 32);
        out[rank] = u2f(u);                               // top_scores (bit-exact)
        const float* cp = cls + (size_t)idx * 3;
        float c0 = cp[0], c1 = cp[1], c2 = cp[2];
        float mx = c0; int lab = 1;
        if (c1 > mx) { mx = c1; lab = 2; }
        if (c2 > mx) { mx = c2; lab = 3; }
        const float* bp = box + (size_t)idx * 7;
        float* op = out + KTOP + (size_t)rank * 7;        // top_boxes
        #pragma unroll
        for (int q = 0; q < 7; ++q) op[q] = bp[q];
        out[KTOP * 8 + rank] = (float)lab;                // top_labels
    }
}

extern "C" void kernel_launch(void* const* d_in, const int* in_sizes, int n_in,
                              void* d_out, int out_size, void* d_ws, size_t ws_size,
                              hipStream_t stream) {
    const float* cls = (const float*)d_in[0];
    const float* box = (const float*)d_in[1];
    float* out = (float*)d_out;
    int n = in_sizes[0] / 3;

    char* ws = (char*)d_ws;
    uint32_t* hist2  = (uint32_t*)(ws + WS_H2);
    uint32_t* hist1  = (uint32_t*)(ws + WS_H1);
    uint32_t* chunks = (uint32_t*)(ws + WS_CHNK);
    uint32_t* scal   = (uint32_t*)(ws + WS_SCAL);
    uint64_t* cand   = (uint64_t*)(ws + WS_CAND);
    uint32_t* u_arr  = nullptr;
    if (ws_size >= (size_t)WS_U + (size_t)n * 4u)
        u_arr = (uint32_t*)(ws + WS_U);

    const int blocks = 2048, threads = 256;
    z0_zero_small<<<(H1_SIZE + 255) / 256, 256, 0, stream>>>(hist1, scal);
    k1_keys_hist<<<blocks, threads, 0, stream>>>(cls, u_arr, hist1, hist2, n);
    k2_scan1<<<1, 1024, 0, stream>>>(hist1, scal);
    k3_hist2<<<blocks, threads, 0, stream>>>(u_arr, cls, scal, hist2, n);
    k4a_chunks<<<1024, 256, 0, stream>>>(hist2, chunks);
    k4b_scan2<<<1, 1024, 0, stream>>>(hist2, chunks, scal);
    k5_compact<<<blocks, threads, 0, stream>>>(u_arr, cls, scal, cand, &scal[3], n);
    k6_rank_out<<<(CAND_MAX + 1023) / 1024, 1024, 0, stream>>>(cand, &scal[3], cls, box, out);
}

// Round 4
// 183.894 us; speedup vs baseline: 1.6139x; 1.3415x over previous
//
#include <hip/hip_runtime.h>
#include <stdint.h>

#define KTOP 4096
#define H1_SIZE 4096           // histogram over top 12 bits of ordered key
#define H2_SIZE 65536          // histogram over key bits [19:4] within boundary bucket
#define CAND_MAX 8192
#define K6_BLOCKS 128          // CAND_MAX / 64 candidates-per-block

// ---- workspace layout (bytes) ----
// [0, 16384)        hist1 (4096 u32)   -- zeroed by z0
// [16384, 278528)   hist2 (64K u32)    -- zeroed by z0
// [278528, 278560)  scalars: 2=t28 threshold, 3=cand_count -- zeroed by z0
// [278592, 344128)  candidates (8192 u64) -- no zeroing needed
// [344128, +4n)     u array
#define WS_H1    0
#define WS_H2    16384
#define WS_SCAL  278528
#define WS_CAND  278592
#define WS_U     344128
#define WS_ZERO_UINT4 17410    // [0, 278560) as uint4

__device__ __forceinline__ uint32_t f2u(float f) {
    uint32_t b = __float_as_uint(f);
    return (b & 0x80000000u) ? ~b : (b | 0x80000000u);
}

__device__ __forceinline__ float u2f(uint32_t u) {
    uint32_t b = (u & 0x80000000u) ? (u ^ 0x80000000u) : ~u;
    return __uint_as_float(b);
}

__device__ __forceinline__ uint4 group_u(const uint32_t* __restrict__ u_arr,
                                         const float* __restrict__ cls, int g) {
    if (u_arr) return ((const uint4*)u_arr)[g];
    const float4* p = (const float4*)(cls + (size_t)g * 12);
    float4 a = p[0], b = p[1], c = p[2];
    uint4 u;
    u.x = f2u(fmaxf(fmaxf(a.x, a.y), a.z));
    u.y = f2u(fmaxf(fmaxf(a.w, b.x), b.y));
    u.z = f2u(fmaxf(fmaxf(b.z, b.w), c.x));
    u.w = f2u(fmaxf(fmaxf(c.y, c.z), c.w));
    return u;
}

__device__ __forceinline__ uint32_t scalar_u(const float* __restrict__ cls, int i) {
    const float* p = cls + (size_t)i * 3;
    return f2u(fmaxf(fmaxf(p[0], p[1]), p[2]));
}

// z0: zero hist1 + hist2 + scalars (272 KB, one contiguous region).
__global__ void z0_zero(uint4* __restrict__ wsv) {
    int t = blockIdx.x * blockDim.x + threadIdx.x;
    uint4 z = make_uint4(0u, 0u, 0u, 0u);
    if (t < WS_ZERO_UINT4) wsv[t] = z;
}

// K1: compute ordered keys, store u_arr, 12-bit-prefix histogram (LDS agg).
__global__ void k1_keys_hist(const float* __restrict__ cls,
                             uint32_t* __restrict__ u_arr,
                             uint32_t* __restrict__ hist1, int n) {
    __shared__ uint32_t lh[H1_SIZE];
    int stride = gridDim.x * blockDim.x;
    for (int i = threadIdx.x; i < H1_SIZE; i += blockDim.x) lh[i] = 0u;
    __syncthreads();
    int nq = n >> 2;
    for (int g = blockIdx.x * blockDim.x + threadIdx.x; g < nq; g += stride) {
        const float4* p = (const float4*)(cls + (size_t)g * 12);
        float4 a = p[0], b = p[1], c = p[2];
        uint4 u;
        u.x = f2u(fmaxf(fmaxf(a.x, a.y), a.z));
        u.y = f2u(fmaxf(fmaxf(a.w, b.x), b.y));
        u.z = f2u(fmaxf(fmaxf(b.z, b.w), c.x));
        u.w = f2u(fmaxf(fmaxf(c.y, c.z), c.w));
        if (u_arr) ((uint4*)u_arr)[g] = u;
        atomicAdd(&lh[u.x >> 20], 1u);
        atomicAdd(&lh[u.y >> 20], 1u);
        atomicAdd(&lh[u.z >> 20], 1u);
        atomicAdd(&lh[u.w >> 20], 1u);
    }
    int rem = n & 3;
    if (blockIdx.x == 0 && (int)threadIdx.x < rem) {
        int i = (n & ~3) + threadIdx.x;
        uint32_t uu = scalar_u(cls, i);
        if (u_arr) u_arr[i] = uu;
        atomicAdd(&hist1[uu >> 20], 1u);
    }
    __syncthreads();
    for (int i = threadIdx.x; i < H1_SIZE; i += blockDim.x) {
        uint32_t v = lh[i];
        if (v) atomicAdd(&hist1[i], v);
    }
}

// K23: every block redundantly scans hist1 to find boundary bucket b*
// (16 KB L2-hot read + block-local suffix scan), then histograms key
// bits [19:4] for elements in bucket b* into global hist2 (64K bins,
// ~21 elems/bin for this data -> negligible atomic contention).
__global__ void k23_hist2(const uint32_t* __restrict__ u_arr,
                          const float* __restrict__ cls,
                          const uint32_t* __restrict__ hist1,
                          uint32_t* __restrict__ hist2, int n) {
    __shared__ uint32_t ps[256];
    __shared__ uint32_t sh_b;
    int t = threadIdx.x;
    uint32_t hh[16];
    uint32_t sum = 0;
    #pragma unroll
    for (int j = 0; j < 16; ++j) { hh[j] = hist1[t * 16 + j]; sum += hh[j]; }
    ps[t] = sum;
    for (int off = 1; off < 256; off <<= 1) {
        __syncthreads();
        uint32_t v = (t + off < 256) ? ps[t + off] : 0u;
        __syncthreads();
        ps[t] += v;
    }
    uint32_t incl = ps[t];
    uint32_t excl = incl - sum;
    if (excl < KTOP && incl >= KTOP) {          // unique crossing thread
        uint32_t s = excl;
        #pragma unroll
        for (int j = 15; j >= 0; --j) {
            uint32_t ns = s + hh[j];
            if (ns >= KTOP) { sh_b = (uint32_t)(t * 16 + j); break; }
            s = ns;
        }
    }
    __syncthreads();
    uint32_t bstar = sh_b;
    int nq = n >> 2;
    int stride = gridDim.x * blockDim.x;
    for (int g = blockIdx.x * blockDim.x + threadIdx.x; g < nq; g += stride) {
        uint4 u = group_u(u_arr, cls, g);
        if ((u.x >> 20) == bstar) atomicAdd(&hist2[(u.x >> 4) & 0xFFFFu], 1u);
        if ((u.y >> 20) == bstar) atomicAdd(&hist2[(u.y >> 4) & 0xFFFFu], 1u);
        if ((u.z >> 20) == bstar) atomicAdd(&hist2[(u.z >> 4) & 0xFFFFu], 1u);
        if ((u.w >> 20) == bstar) atomicAdd(&hist2[(u.w >> 4) & 0xFFFFu], 1u);
    }
    int rem = n & 3;
    if (blockIdx.x == 0 && (int)threadIdx.x < rem) {
        int i = (n & ~3) + threadIdx.x;
        uint32_t uu = u_arr ? u_arr[i] : scalar_u(cls, i);
        if ((uu >> 20) == bstar) atomicAdd(&hist2[(uu >> 4) & 0xFFFFu], 1u);
    }
}

// K4: single block. Recompute b* + count_above from hist1, then suffix-scan
// hist2 (64 bins/thread: chunk sums -> block scan -> walk) to find the 28-bit
// threshold t28. Writes scal[2] = t28.
__global__ void __launch_bounds__(1024) k4_resolve(const uint32_t* __restrict__ hist1,
                                                   const uint32_t* __restrict__ hist2,
                                                   uint32_t* __restrict__ scal) {
    __shared__ uint32_t ps[1024];
    __shared__ uint32_t sh_b, sh_ca;
    int t = threadIdx.x;
    // ---- pass A: boundary bucket from hist1 ----
    uint32_t h0 = hist1[4 * t], h1 = hist1[4 * t + 1];
    uint32_t h2 = hist1[4 * t + 2], h3 = hist1[4 * t + 3];
    uint32_t sum = h0 + h1 + h2 + h3;
    ps[t] = sum;
    for (int off = 1; off < 1024; off <<= 1) {
        __syncthreads();
        uint32_t v = (t + off < 1024) ? ps[t + off] : 0u;
        __syncthreads();
        ps[t] += v;
    }
    uint32_t incl = ps[t];
    uint32_t excl = incl - sum;
    if (excl < KTOP && incl >= KTOP) {
        uint32_t hh[4] = {h0, h1, h2, h3};
        uint32_t s = excl;
        #pragma unroll
        for (int j = 3; j >= 0; --j) {
            uint32_t ns = s + hh[j];
            if (ns >= KTOP) { sh_b = (uint32_t)(4 * t + j); sh_ca = s; break; }
            s = ns;
        }
    }
    __syncthreads();
    uint32_t bstar = sh_b;
    uint32_t krem = (uint32_t)KTOP - sh_ca;     // in [1, 4096]
    // ---- pass B: 16-bit threshold from hist2 ----
    uint32_t csum = 0;
    for (int j = 0; j < 64; ++j) csum += hist2[t * 64 + j];
    ps[t] = csum;
    for (int off = 1; off < 1024; off <<= 1) {
        __syncthreads();
        uint32_t v = (t + off < 1024) ? ps[t + off] : 0u;
        __syncthreads();
        ps[t] += v;
    }
    uint32_t incl2 = ps[t];
    uint32_t excl2 = incl2 - csum;
    if (excl2 < krem && incl2 >= krem) {
        uint32_t s = excl2;
        for (int j = 63; j >= 0; --j) {
            uint32_t ns = s + hist2[t * 64 + j];
            if (ns >= krem) { scal[2] = (bstar << 16) | (uint32_t)(t * 64 + j); break; }
            s = ns;
        }
    }
}

// K5: compact all keys with (u>>4) >= t28 as 64-bit sortable (u<<32)|~idx.
// For this data the boundary 28-bit bin holds ~20-50 elems -> m ~= 4150.
__global__ void k5_compact(const uint32_t* __restrict__ u_arr,
                           const float* __restrict__ cls,
                           const uint32_t* __restrict__ scal,
                           uint64_t* __restrict__ cand,
                           uint32_t* __restrict__ cnt, int n) {
    uint32_t t28 = scal[2];
    int nq = n >> 2;
    int stride = gridDim.x * blockDim.x;
    for (int g = blockIdx.x * blockDim.x + threadIdx.x; g < nq; g += stride) {
        uint4 u = group_u(u_arr, cls, g);
        uint32_t b = (uint32_t)g * 4u;
        if ((u.x >> 4) >= t28) { uint32_t p = atomicAdd(cnt, 1u); if (p < CAND_MAX) cand[p] = ((uint64_t)u.x << 32) | (uint32_t)~(b + 0u); }
        if ((u.y >> 4) >= t28) { uint32_t p = atomicAdd(cnt, 1u); if (p < CAND_MAX) cand[p] = ((uint64_t)u.y << 32) | (uint32_t)~(b + 1u); }
        if ((u.z >> 4) >= t28) { uint32_t p = atomicAdd(cnt, 1u); if (p < CAND_MAX) cand[p] = ((uint64_t)u.z << 32) | (uint32_t)~(b + 2u); }
        if ((u.w >> 4) >= t28) { uint32_t p = atomicAdd(cnt, 1u); if (p < CAND_MAX) cand[p] = ((uint64_t)u.w << 32) | (uint32_t)~(b + 3u); }
    }
    int rem = n & 3;
    if (blockIdx.x == 0 && (int)threadIdx.x < rem) {
        int i = (n & ~3) + threadIdx.x;
        uint32_t uu = u_arr ? u_arr[i] : scalar_u(cls, i);
        if ((uu >> 4) >= t28) { uint32_t p = atomicAdd(cnt, 1u); if (p < CAND_MAX) cand[p] = ((uint64_t)uu << 32) | (uint32_t)~((uint32_t)i); }
    }
}

// K6: cooperative counting-rank. 128 blocks x 1024 threads; 16 threads per
// candidate, each scanning m/16 keys (odd chunk -> conflict-free-ish banks;
// 4 candidate groups per wave read identical addresses -> LDS broadcast).
// rank = #{j : key_j > key_i} reproduces (value desc, index asc) exactly
// since keys (u<<32)|~idx are unique.
__global__ void __launch_bounds__(1024) k6_rank_out(const uint64_t* __restrict__ cand,
                                                    const uint32_t* __restrict__ cnt,
                                                    const float* __restrict__ cls,
                                                    const float* __restrict__ box,
                                                    float* __restrict__ out) {
    __shared__ uint64_t s[CAND_MAX];
    uint32_t m = *cnt;
    if (m > CAND_MAX) m = CAND_MAX;
    for (int j = threadIdx.x; j < CAND_MAX; j += 1024)
        s[j] = (j < (int)m) ? cand[j] : 0ull;   // pad 0: real keys have bit63 set
    __syncthreads();
    int t = threadIdx.x;
    int slice = t & 15;
    int i = blockIdx.x * 64 + (t >> 4);
    int mm = (int)m;
    uint64_t key = (i < mm) ? s[i] : ~0ull;
    int chunk = ((mm + 15) >> 4) | 1;           // odd -> spread banks
    int j0 = slice * chunk;
    int j1 = j0 + chunk; if (j1 > mm) j1 = mm;
    uint32_t r = 0;
    int j = j0;
    for (; j + 4 <= j1; j += 4) {
        r += (uint32_t)(s[j + 0] > key);
        r += (uint32_t)(s[j + 1] > key);
        r += (uint32_t)(s[j + 2] > key);
        r += (uint32_t)(s[j + 3] > key);
    }
    for (; j < j1; ++j) r += (uint32_t)(s[j] > key);
    #pragma unroll
    for (int off = 8; off > 0; off >>= 1) r += __shfl_down(r, off, 16);
    if (slice == 0 && i < mm) {
        uint32_t rank = r;
        if (rank < KTOP) {
            uint32_t idx = ~(uint32_t)key;
            uint32_t u = (uint32_t)(key >> 32);
            out[rank] = u2f(u);                               // top_scores (bit-exact)
            const float* cp = cls + (size_t)idx * 3;
            float c0 = cp[0], c1 = cp[1], c2 = cp[2];
            float mx = c0; int lab = 1;
            if (c1 > mx) { mx = c1; lab = 2; }
            if (c2 > mx) { mx = c2; lab = 3; }
            const float* bp = box + (size_t)idx * 7;
            float* op = out + KTOP + (size_t)rank * 7;        // top_boxes
            #pragma unroll
            for (int q = 0; q < 7; ++q) op[q] = bp[q];
            out[KTOP * 8 + rank] = (float)lab;                // top_labels
        }
    }
}

extern "C" void kernel_launch(void* const* d_in, const int* in_sizes, int n_in,
                              void* d_out, int out_size, void* d_ws, size_t ws_size,
                              hipStream_t stream) {
    const float* cls = (const float*)d_in[0];
    const float* box = (const float*)d_in[1];
    float* out = (float*)d_out;
    int n = in_sizes[0] / 3;

    char* ws = (char*)d_ws;
    uint32_t* hist1 = (uint32_t*)(ws + WS_H1);
    uint32_t* hist2 = (uint32_t*)(ws + WS_H2);
    uint32_t* scal  = (uint32_t*)(ws + WS_SCAL);
    uint64_t* cand  = (uint64_t*)(ws + WS_CAND);
    uint32_t* u_arr = nullptr;
    if (ws_size >= (size_t)WS_U + (size_t)n * 4u)
        u_arr = (uint32_t*)(ws + WS_U);

    const int blocks = 2048, threads = 256;
    z0_zero<<<(WS_ZERO_UINT4 + 255) / 256, 256, 0, stream>>>((uint4*)ws);
    k1_keys_hist<<<blocks, threads, 0, stream>>>(cls, u_arr, hist1, n);
    k23_hist2<<<blocks, threads, 0, stream>>>(u_arr, cls, hist1, hist2, n);
    k4_resolve<<<1, 1024, 0, stream>>>(hist1, hist2, scal);
    k5_compact<<<blocks, threads, 0, stream>>>(u_arr, cls, scal, cand, &scal[3], n);
    k6_rank_out<<<K6_BLOCKS, 1024, 0, stream>>>(cand, &scal[3], cls, box, out);
}